// Round 3
// baseline (81.371 us; speedup 1.0000x reference)
//
#include <hip/hip_runtime.h>
#include <math.h>

#pragma clang fp contract(off)

#define NPIX 1024

// ---------------------------------------------------------------------------
// 9-tap gaussian (sigma=1, lw=4): phi in f64, normalized with numpy's pairwise
// sum order, cast to f32 — matches jnp.asarray(GAUSS_K, float32).
// ---------------------------------------------------------------------------
__device__ __forceinline__ void compute_gk(float gk[9]) {
    double phi[9];
    #pragma unroll
    for (int t = 0; t < 9; ++t) {
        double d = (double)(t - 4);
        phi[t] = exp(-0.5 * d * d);
    }
    // numpy pairwise_sum order for n=9:
    double s = (((phi[0] + phi[1]) + (phi[2] + phi[3])) +
                ((phi[4] + phi[5]) + (phi[6] + phi[7]))) + phi[8];
    #pragma unroll
    for (int t = 0; t < 9; ++t) gk[t] = (float)(phi[t] / s);
}

// zero-padded / edge-clamped LDS reads of a 32x32 float tile
__device__ __forceinline__ float ldz(const float* b, int i, int j) {
    return (i >= 0 && i < 32 && j >= 0 && j < 32) ? b[(i << 5) + j] : 0.0f;
}
__device__ __forceinline__ float ldc(const float* b, int i, int j) {
    i = i < 0 ? 0 : (i > 31 ? 31 : i);
    j = j < 0 ? 0 : (j > 31 ? 31 : j);
    return b[(i << 5) + j];
}

// gaussian blur along H (rows), zero padding; Eigen-style FMA chain, taps ascending
__device__ __forceinline__ void blur_h(const float* in, float* out, const float gk[9], int tid) {
    #pragma unroll
    for (int k = 0; k < 4; ++k) {
        int p = tid + (k << 8), i = p >> 5, j = p & 31;
        float s = 0.0f;
        #pragma unroll
        for (int t = 0; t < 9; ++t) s = __fmaf_rn(gk[t], ldz(in, i + t - 4, j), s);
        out[p] = s;
    }
}
// gaussian blur along W, zero padding; FMA chain ascending
__device__ __forceinline__ void blur_w(const float* in, float* out, const float gk[9], int tid) {
    #pragma unroll
    for (int k = 0; k < 4; ++k) {
        int p = tid + (k << 8), i = p >> 5, j = p & 31;
        float s = 0.0f;
        #pragma unroll
        for (int t = 0; t < 9; ++t) s = __fmaf_rn(gk[t], ldz(in, i, j + t - 4), s);
        out[p] = s;
    }
}

// NMS interpolation check: ip = mag[p2]*w + mag[p1]*(1-w); im likewise; both <= m
__device__ __forceinline__ bool nms2(const float* mag, int i, int j, float m, float w,
                                     int p2i, int p2j, int p1i, int p1j,
                                     int m2i, int m2j, int m1i, int m1j) {
    float omw = 1.0f - w;
    float ip = ldz(mag, i + p2i, j + p2j) * w + ldz(mag, i + p1i, j + p1j) * omw;
    float im = ldz(mag, i + m2i, j + m2j) * w + ldz(mag, i + m1i, j + m1j) * omw;
    return (ip <= m) && (im <= m);
}

// ---------------------------------------------------------------------------
// Kernel A: bleed = gauss(mask), er = erode3x3(mask!=0) & (mag2(batch0) > 0)
// ---------------------------------------------------------------------------
__global__ __launch_bounds__(256) void canny_pre(const float* __restrict__ x,
                                                 const float* __restrict__ mask,
                                                 float* __restrict__ ws_bleed,
                                                 unsigned int* __restrict__ ws_er) {
    __shared__ float A[NPIX], Bf[NPIX], C[NPIX], D[NPIX], BL[NPIX];
    __shared__ unsigned int er32[32];
    const int tid = threadIdx.x;
    float gk[9];
    compute_gk(gk);

    #pragma unroll
    for (int k = 0; k < 4; ++k) { int p = tid + (k << 8); A[p] = mask[p]; }
    if (tid < 32) er32[tid] = 0u;
    __syncthreads();

    blur_h(A, Bf, gk, tid);
    __syncthreads();
    blur_w(Bf, BL, gk, tid);
    #pragma unroll
    for (int k = 0; k < 4; ++k) { int p = tid + (k << 8); ws_bleed[p] = BL[p]; }

    // binary erosion of (mask != 0), full 3x3, zero border (A still holds mask)
    bool er2d[4];
    #pragma unroll
    for (int k = 0; k < 4; ++k) {
        int p = tid + (k << 8), i = p >> 5, j = p & 31;
        bool e = true;
        for (int di = -1; di <= 1; ++di)
            for (int dj = -1; dj <= 1; ++dj) {
                int ii = i + di, jj = j + dj;
                e = e && (ii >= 0 && ii < 32 && jj >= 0 && jj < 32) && (A[(ii << 5) + jj] != 0.0f);
            }
        er2d[k] = e;
    }
    __syncthreads();

    // batch-0 pipeline to mag2
    #pragma unroll
    for (int k = 0; k < 4; ++k) {
        int p = tid + (k << 8);
        float r = x[p]            * 0.5f + 0.5f;
        float g = x[p + NPIX]     * 0.5f + 0.5f;
        float b = x[p + 2 * NPIX] * 0.5f + 0.5f;
        A[p] = r * 0.299f + g * 0.587f + b * 0.114f;
    }
    __syncthreads();
    blur_h(A, Bf, gk, tid);
    __syncthreads();
    blur_w(Bf, A, gk, tid);
    #pragma unroll
    for (int k = 0; k < 4; ++k) { int p = tid + (k << 8); A[p] = A[p] / (BL[p] + 1e-12f); }
    __syncthreads();
    // d/dW -> Bf (edge clamp)
    #pragma unroll
    for (int k = 0; k < 4; ++k) { int p = tid + (k << 8), i = p >> 5, j = p & 31;
        Bf[p] = ldc(A, i, j + 1) - ldc(A, i, j - 1); }
    __syncthreads();
    // jsob -> C
    #pragma unroll
    for (int k = 0; k < 4; ++k) { int p = tid + (k << 8), i = p >> 5, j = p & 31;
        C[p] = (ldc(Bf, i - 1, j) + 2.0f * ldc(Bf, i, j)) + ldc(Bf, i + 1, j); }
    __syncthreads();
    // d/dH -> Bf
    #pragma unroll
    for (int k = 0; k < 4; ++k) { int p = tid + (k << 8), i = p >> 5, j = p & 31;
        Bf[p] = ldc(A, i + 1, j) - ldc(A, i - 1, j); }
    __syncthreads();
    // isob -> D
    #pragma unroll
    for (int k = 0; k < 4; ++k) { int p = tid + (k << 8), i = p >> 5, j = p & 31;
        D[p] = (ldc(Bf, i, j - 1) + 2.0f * ldc(Bf, i, j)) + ldc(Bf, i, j + 1); }
    __syncthreads();
    #pragma unroll
    for (int k = 0; k < 4; ++k) {
        int p = tid + (k << 8), i = p >> 5, j = p & 31;
        if (er2d[k]) {
            float m2 = D[p] * D[p] + C[p] * C[p];  // isob^2 + jsob^2
            if (m2 > 0.0f) atomicOr(&er32[i], 1u << j);
        }
    }
    __syncthreads();
    if (tid < 32) ws_er[tid] = er32[tid];
}

// ---------------------------------------------------------------------------
// Kernel B: one block per image. Full pipeline + NMS + hysteresis flood fill.
// ---------------------------------------------------------------------------
__global__ __launch_bounds__(256) void canny_main(const float* __restrict__ x,
                                                  const float* __restrict__ ws_bleed,
                                                  const unsigned int* __restrict__ ws_er,
                                                  float* __restrict__ out) {
    __shared__ float A[NPIX], Bf[NPIX], C[NPIX], D[NPIX];
    __shared__ unsigned int er[32], hi32[32], lo32[32], fin32[32];
    const int tid = threadIdx.x;
    const int b = blockIdx.x;
    float gk[9];
    compute_gk(gk);

    const float* xb = x + (size_t)b * 3 * NPIX;
    #pragma unroll
    for (int k = 0; k < 4; ++k) {
        int p = tid + (k << 8);
        float r  = xb[p]            * 0.5f + 0.5f;
        float g  = xb[p + NPIX]     * 0.5f + 0.5f;
        float bl = xb[p + 2 * NPIX] * 0.5f + 0.5f;
        A[p] = r * 0.299f + g * 0.587f + bl * 0.114f;
    }
    if (tid < 32) { er[tid] = ws_er[tid]; hi32[tid] = 0u; lo32[tid] = 0u; }
    __syncthreads();

    blur_h(A, Bf, gk, tid);
    __syncthreads();
    blur_w(Bf, A, gk, tid);            // reads Bf, writes own A[p]
    #pragma unroll
    for (int k = 0; k < 4; ++k) { int p = tid + (k << 8); A[p] = A[p] / (ws_bleed[p] + 1e-12f); }
    __syncthreads();                    // A = sm
    // d/dW -> Bf (edge clamp)
    #pragma unroll
    for (int k = 0; k < 4; ++k) { int p = tid + (k << 8), i = p >> 5, j = p & 31;
        Bf[p] = ldc(A, i, j + 1) - ldc(A, i, j - 1); }
    __syncthreads();
    // jsob -> C
    #pragma unroll
    for (int k = 0; k < 4; ++k) { int p = tid + (k << 8), i = p >> 5, j = p & 31;
        C[p] = (ldc(Bf, i - 1, j) + 2.0f * ldc(Bf, i, j)) + ldc(Bf, i + 1, j); }
    __syncthreads();
    // d/dH -> Bf
    #pragma unroll
    for (int k = 0; k < 4; ++k) { int p = tid + (k << 8), i = p >> 5, j = p & 31;
        Bf[p] = ldc(A, i + 1, j) - ldc(A, i - 1, j); }
    __syncthreads();
    // isob -> D
    #pragma unroll
    for (int k = 0; k < 4; ++k) { int p = tid + (k << 8), i = p >> 5, j = p & 31;
        D[p] = (ldc(Bf, i, j - 1) + 2.0f * ldc(Bf, i, j)) + ldc(Bf, i, j + 1); }
    __syncthreads();
    // mag -> A: sqrt((isob^2 + jsob^2) + 1e-9)
    #pragma unroll
    for (int k = 0; k < 4; ++k) { int p = tid + (k << 8);
        A[p] = sqrtf((D[p] * D[p] + C[p] * C[p]) + 1e-9f); }
    __syncthreads();

    // NMS: 4 octants evaluated in order, later overwrite (matches ref loop)
    #pragma unroll
    for (int k = 0; k < 4; ++k) {
        int p = tid + (k << 8), i = p >> 5, j = p & 31;
        if ((er[i] >> j) & 1u) {
            float iv = D[p], jv = C[p], m = A[p];
            float ai = fabsf(iv), aj = fabsf(jv);
            bool same = (iv >= 0.0f && jv >= 0.0f) || (iv <= 0.0f && jv <= 0.0f);
            bool opp  = (iv <= 0.0f && jv >= 0.0f) || (iv >= 0.0f && jv <= 0.0f);
            float ais = ai > 0.0f ? ai : 1.0f;
            float ajs = aj > 0.0f ? aj : 1.0f;
            bool lm = false;
            if (same && ai >= aj) lm = nms2(A, i, j, m, aj / (ai + 1e-9f),  1, 1,  1, 0, -1, -1, -1,  0);
            if (same && ai <= aj) lm = nms2(A, i, j, m, ai / ajs,           1, 1,  0, 1, -1, -1,  0, -1);
            if (opp  && ai <= aj) lm = nms2(A, i, j, m, ai / ajs,          -1, 1,  0, 1,  1, -1,  0, -1);
            if (opp  && ai >= aj) lm = nms2(A, i, j, m, aj / ais,          -1, 1, -1, 0,  1, -1,  1,  0);
            if (lm) {
                if (m >= 0.2f) atomicOr(&hi32[i], 1u << j);
                if (m >= 0.1f) atomicOr(&lo32[i], 1u << j);
            }
        }
    }
    __syncthreads();

    // hysteresis: 8-connected flood of `low` seeded at `high`; wave 0, row-per-lane
    if (tid < 64) {
        unsigned int lw  = (tid < 32) ? lo32[tid] : 0u;
        unsigned int cur = (tid < 32) ? hi32[tid] : 0u;
        for (;;) {
            unsigned int sp  = cur | (cur << 1) | (cur >> 1);
            unsigned int upv = (unsigned int)__shfl((int)sp, (tid + 63) & 63, 64);
            if (tid == 0) upv = 0u;
            unsigned int dnv = (unsigned int)__shfl((int)sp, (tid + 1) & 63, 64);
            unsigned int nxt = (sp | upv | dnv) & lw;
            bool ch = (nxt != cur);
            cur = nxt;
            if (__ballot((int)ch) == 0ull) break;
        }
        if (tid < 32) fin32[tid] = cur;
    }
    __syncthreads();

    float* ob = out + (size_t)b * NPIX;
    #pragma unroll
    for (int k = 0; k < 4; ++k) {
        int p = tid + (k << 8), i = p >> 5, j = p & 31;
        ob[p] = ((fin32[i] >> j) & 1u) ? 1.0f : -1.0f;
    }
}

extern "C" void kernel_launch(void* const* d_in, const int* in_sizes, int n_in,
                              void* d_out, int out_size, void* d_ws, size_t ws_size,
                              hipStream_t stream) {
    const float* x    = (const float*)d_in[0];
    const float* mask = (const float*)d_in[1];
    float* out        = (float*)d_out;
    float* ws_bleed   = (float*)d_ws;
    unsigned int* ws_er = (unsigned int*)(ws_bleed + NPIX);
    int Bn = in_sizes[0] / (3 * NPIX);

    hipLaunchKernelGGL(canny_pre, dim3(1), dim3(256), 0, stream, x, mask, ws_bleed, ws_er);
    hipLaunchKernelGGL(canny_main, dim3(Bn), dim3(256), 0, stream, x, ws_bleed, ws_er, out);
}

// Round 4
// 62.938 us; speedup vs baseline: 1.2929x; 1.2929x over previous
//
#include <hip/hip_runtime.h>
#include <math.h>

#pragma clang fp contract(off)

#define NPIX 1024

// ---------------------------------------------------------------------------
// 9-tap gaussian (sigma=1, lw=4): phi in f64, normalized with numpy's pairwise
// sum order, cast to f32 — matches jnp.asarray(GAUSS_K, float32).
// Only computed in canny_pre (f64 exp is expensive); main reads ws_gk.
// ---------------------------------------------------------------------------
__device__ __forceinline__ void compute_gk(float gk[9]) {
    double phi[9];
    #pragma unroll
    for (int t = 0; t < 9; ++t) {
        double d = (double)(t - 4);
        phi[t] = exp(-0.5 * d * d);
    }
    double s = (((phi[0] + phi[1]) + (phi[2] + phi[3])) +
                ((phi[4] + phi[5]) + (phi[6] + phi[7]))) + phi[8];
    #pragma unroll
    for (int t = 0; t < 9; ++t) gk[t] = (float)(phi[t] / s);
}

// zero-padded / edge-clamped reads of a 32x32 float tile (row stride 32)
__device__ __forceinline__ float ldz(const float* b, int i, int j) {
    return (i >= 0 && i < 32 && j >= 0 && j < 32) ? b[(i << 5) + j] : 0.0f;
}
__device__ __forceinline__ float ldc(const float* b, int i, int j) {
    i = i < 0 ? 0 : (i > 31 ? 31 : i);
    j = j < 0 ? 0 : (j > 31 ? 31 : j);
    return b[(i << 5) + j];
}

// NMS interpolation check on plain 32x32 mag tile
__device__ __forceinline__ bool nms2(const float* mag, int i, int j, float m, float w,
                                     int p2i, int p2j, int p1i, int p1j,
                                     int m2i, int m2j, int m1i, int m1j) {
    float omw = 1.0f - w;
    float ip = ldz(mag, i + p2i, j + p2j) * w + ldz(mag, i + p1i, j + p1j) * omw;
    float im = ldz(mag, i + m2i, j + m2j) * w + ldz(mag, i + m1i, j + m1j) * omw;
    return (ip <= m) && (im <= m);
}

// ---------------------------------------------------------------------------
// Kernel A (1 block): gk -> ws_gk; bleed = gauss(mask) -> ws_bleed;
// er = erode3x3(mask!=0) & (mag2(batch0) > 0) -> ws_er.  Round-3-proven code.
// ---------------------------------------------------------------------------
__global__ __launch_bounds__(256) void canny_pre(const float* __restrict__ x,
                                                 const float* __restrict__ mask,
                                                 float* __restrict__ ws_bleed,
                                                 unsigned int* __restrict__ ws_er,
                                                 float* __restrict__ ws_gk) {
    __shared__ float A[NPIX], Bf[NPIX], C[NPIX], D[NPIX], BL[NPIX];
    __shared__ unsigned int er32[32];
    const int tid = threadIdx.x;
    float gk[9];
    compute_gk(gk);
    if (tid < 9) ws_gk[tid] = gk[tid];

    #pragma unroll
    for (int k = 0; k < 4; ++k) { int p = tid + (k << 8); A[p] = mask[p]; }
    if (tid < 32) er32[tid] = 0u;
    __syncthreads();

    // blur H (zero pad), FMA chain
    #pragma unroll
    for (int k = 0; k < 4; ++k) {
        int p = tid + (k << 8), i = p >> 5, j = p & 31;
        float s = 0.0f;
        #pragma unroll
        for (int t = 0; t < 9; ++t) s = __fmaf_rn(gk[t], ldz(A, i + t - 4, j), s);
        Bf[p] = s;
    }
    __syncthreads();
    #pragma unroll
    for (int k = 0; k < 4; ++k) {
        int p = tid + (k << 8), i = p >> 5, j = p & 31;
        float s = 0.0f;
        #pragma unroll
        for (int t = 0; t < 9; ++t) s = __fmaf_rn(gk[t], ldz(Bf, i, j + t - 4), s);
        BL[p] = s;
        ws_bleed[p] = s;
    }

    bool er2d[4];
    #pragma unroll
    for (int k = 0; k < 4; ++k) {
        int p = tid + (k << 8), i = p >> 5, j = p & 31;
        bool e = true;
        for (int di = -1; di <= 1; ++di)
            for (int dj = -1; dj <= 1; ++dj) {
                int ii = i + di, jj = j + dj;
                e = e && (ii >= 0 && ii < 32 && jj >= 0 && jj < 32) && (A[(ii << 5) + jj] != 0.0f);
            }
        er2d[k] = e;
    }
    __syncthreads();

    #pragma unroll
    for (int k = 0; k < 4; ++k) {
        int p = tid + (k << 8);
        float r = x[p]            * 0.5f + 0.5f;
        float g = x[p + NPIX]     * 0.5f + 0.5f;
        float b = x[p + 2 * NPIX] * 0.5f + 0.5f;
        A[p] = r * 0.299f + g * 0.587f + b * 0.114f;
    }
    __syncthreads();
    #pragma unroll
    for (int k = 0; k < 4; ++k) {
        int p = tid + (k << 8), i = p >> 5, j = p & 31;
        float s = 0.0f;
        #pragma unroll
        for (int t = 0; t < 9; ++t) s = __fmaf_rn(gk[t], ldz(A, i + t - 4, j), s);
        Bf[p] = s;
    }
    __syncthreads();
    #pragma unroll
    for (int k = 0; k < 4; ++k) {
        int p = tid + (k << 8), i = p >> 5, j = p & 31;
        float s = 0.0f;
        #pragma unroll
        for (int t = 0; t < 9; ++t) s = __fmaf_rn(gk[t], ldz(Bf, i, j + t - 4), s);
        A[p] = s;
    }
    __syncthreads();
    #pragma unroll
    for (int k = 0; k < 4; ++k) { int p = tid + (k << 8); A[p] = A[p] / (BL[p] + 1e-12f); }
    __syncthreads();
    // d/dW -> Bf (edge clamp)
    #pragma unroll
    for (int k = 0; k < 4; ++k) { int p = tid + (k << 8), i = p >> 5, j = p & 31;
        Bf[p] = ldc(A, i, j + 1) - ldc(A, i, j - 1); }
    __syncthreads();
    // jsob -> C
    #pragma unroll
    for (int k = 0; k < 4; ++k) { int p = tid + (k << 8), i = p >> 5, j = p & 31;
        C[p] = (ldc(Bf, i - 1, j) + 2.0f * ldc(Bf, i, j)) + ldc(Bf, i + 1, j); }
    __syncthreads();
    // d/dH -> Bf
    #pragma unroll
    for (int k = 0; k < 4; ++k) { int p = tid + (k << 8), i = p >> 5, j = p & 31;
        Bf[p] = ldc(A, i + 1, j) - ldc(A, i - 1, j); }
    __syncthreads();
    // isob -> D
    #pragma unroll
    for (int k = 0; k < 4; ++k) { int p = tid + (k << 8), i = p >> 5, j = p & 31;
        D[p] = (ldc(Bf, i, j - 1) + 2.0f * ldc(Bf, i, j)) + ldc(Bf, i, j + 1); }
    __syncthreads();
    #pragma unroll
    for (int k = 0; k < 4; ++k) {
        int p = tid + (k << 8), i = p >> 5, j = p & 31;
        if (er2d[k]) {
            float m2 = D[p] * D[p] + C[p] * C[p];
            if (m2 > 0.0f) atomicOr(&er32[i], 1u << j);
        }
    }
    __syncthreads();
    if (tid < 32) ws_er[tid] = er32[tid];
}

// ---------------------------------------------------------------------------
// Kernel B: one block per image.
// LDS: APAD 40x32 (4 zero-guard rows top/bottom), BPAD 32x40 (4 zero-guard
// cols each side), M 32x32. Sobel fused (jsob/isob in registers), masks via
// per-wave ballot (no atomics).
// ---------------------------------------------------------------------------
__global__ __launch_bounds__(256) void canny_main(const float* __restrict__ x,
                                                  const float* __restrict__ ws_bleed,
                                                  const unsigned int* __restrict__ ws_er,
                                                  const float* __restrict__ ws_gk,
                                                  float* __restrict__ out) {
    __shared__ float APAD[40 * 32];   // (i+4)*32 + j
    __shared__ float BPAD[32 * 40];   // i*40 + (j+4)
    __shared__ float M[NPIX];
    __shared__ unsigned int er[32], hi32[32], lo32[32], fin32[32];
    const int tid = threadIdx.x;
    const int b = blockIdx.x;

    float gk[9];
    #pragma unroll
    for (int t = 0; t < 9; ++t) gk[t] = ws_gk[t];

    // zero guards: APAD rows 0..3 & 36..39 (256 floats), BPAD cols (256 floats)
    APAD[tid < 128 ? tid : 1024 + tid] = 0.0f;
    { int r = tid >> 3, c8 = tid & 7; BPAD[r * 40 + c8 + (c8 < 4 ? 0 : 32)] = 0.0f; }
    if (tid < 32) er[tid] = ws_er[tid];

    // gray via float4 channel loads: this thread covers p = 4*tid .. 4*tid+3
    {
        const float4* xr = (const float4*)(x + (size_t)b * 3 * NPIX);
        float4 r4 = xr[tid];
        float4 g4 = xr[tid + 256];
        float4 b4 = xr[tid + 512];
        int p = tid << 2, i = p >> 5, j = p & 31;
        float4 gy;
        gy.x = (r4.x * 0.5f + 0.5f) * 0.299f + (g4.x * 0.5f + 0.5f) * 0.587f + (b4.x * 0.5f + 0.5f) * 0.114f;
        gy.y = (r4.y * 0.5f + 0.5f) * 0.299f + (g4.y * 0.5f + 0.5f) * 0.587f + (b4.y * 0.5f + 0.5f) * 0.114f;
        gy.z = (r4.z * 0.5f + 0.5f) * 0.299f + (g4.z * 0.5f + 0.5f) * 0.587f + (b4.z * 0.5f + 0.5f) * 0.114f;
        gy.w = (r4.w * 0.5f + 0.5f) * 0.299f + (g4.w * 0.5f + 0.5f) * 0.587f + (b4.w * 0.5f + 0.5f) * 0.114f;
        *(float4*)&APAD[((i + 4) << 5) + j] = gy;
    }
    __syncthreads();

    // gaussian blur along H: read APAD (guarded), write BPAD interior
    #pragma unroll
    for (int k = 0; k < 4; ++k) {
        int p = tid + (k << 8), i = p >> 5, j = p & 31;
        float s = 0.0f;
        #pragma unroll
        for (int t = 0; t < 9; ++t) s = __fmaf_rn(gk[t], APAD[((i + t) << 5) + j], s);
        BPAD[i * 40 + j + 4] = s;
    }
    __syncthreads();

    // gaussian blur along W + divide by bleed: read BPAD (guarded), write APAD interior
    #pragma unroll
    for (int k = 0; k < 4; ++k) {
        int p = tid + (k << 8), i = p >> 5, j = p & 31;
        float s = 0.0f;
        #pragma unroll
        for (int t = 0; t < 9; ++t) s = __fmaf_rn(gk[t], BPAD[i * 40 + j + t], s);
        APAD[((i + 4) << 5) + j] = s / (ws_bleed[p] + 1e-12f);
    }
    __syncthreads();

    // fused sobel + mag: read sm from APAD interior (clamped), jsob/isob -> regs, mag -> M
    float jsr[4], isr[4];
    const float* S = &APAD[4 << 5];   // S[(i<<5)+j] == sm(i,j), clamp keeps us in interior
    #pragma unroll
    for (int k = 0; k < 4; ++k) {
        int p = tid + (k << 8), i = p >> 5, j = p & 31;
        int im1 = i > 0 ? i - 1 : 0, ip1 = i < 31 ? i + 1 : 31;
        int jm1 = j > 0 ? j - 1 : 0, jp1 = j < 31 ? j + 1 : 31;
        // jsob: tmp(r) = S(r, j+1c) - S(r, j-1c); jsob = (tmp(i-1c) + 2*tmp(i)) + tmp(i+1c)
        float tm = S[(im1 << 5) + jp1] - S[(im1 << 5) + jm1];
        float t0 = S[(i   << 5) + jp1] - S[(i   << 5) + jm1];
        float tp = S[(ip1 << 5) + jp1] - S[(ip1 << 5) + jm1];
        float jsob = (tm + 2.0f * t0) + tp;
        // isob: u(c) = S(i+1c, c) - S(i-1c, c); isob = (u(j-1c) + 2*u(j)) + u(j+1c)
        float um = S[(ip1 << 5) + jm1] - S[(im1 << 5) + jm1];
        float u0 = S[(ip1 << 5) + j  ] - S[(im1 << 5) + j  ];
        float up = S[(ip1 << 5) + jp1] - S[(im1 << 5) + jp1];
        float isob = (um + 2.0f * u0) + up;
        jsr[k] = jsob; isr[k] = isob;
        M[p] = sqrtf((isob * isob + jsob * jsob) + 1e-9f);
    }
    __syncthreads();

    // NMS (all lanes compute; er-masked before ballot); per-wave ballot -> row masks
    #pragma unroll
    for (int k = 0; k < 4; ++k) {
        int p = tid + (k << 8), i = p >> 5, j = p & 31;
        float iv = isr[k], jv = jsr[k], m = M[p];
        float ai = fabsf(iv), aj = fabsf(jv);
        bool same = (iv >= 0.0f && jv >= 0.0f) || (iv <= 0.0f && jv <= 0.0f);
        bool opp  = (iv <= 0.0f && jv >= 0.0f) || (iv >= 0.0f && jv <= 0.0f);
        float ais = ai > 0.0f ? ai : 1.0f;
        float ajs = aj > 0.0f ? aj : 1.0f;
        bool lm = false;
        if (same && ai >= aj) lm = nms2(M, i, j, m, aj / (ai + 1e-9f),  1, 1,  1, 0, -1, -1, -1,  0);
        if (same && ai <= aj) lm = nms2(M, i, j, m, ai / ajs,           1, 1,  0, 1, -1, -1,  0, -1);
        if (opp  && ai <= aj) lm = nms2(M, i, j, m, ai / ajs,          -1, 1,  0, 1,  1, -1,  0, -1);
        if (opp  && ai >= aj) lm = nms2(M, i, j, m, aj / ais,          -1, 1, -1, 0,  1, -1,  1,  0);
        bool eb = (er[i] >> j) & 1u;
        unsigned long long bh = __ballot(lm && eb && (m >= 0.2f));
        unsigned long long bl = __ballot(lm && eb && (m >= 0.1f));
        if ((tid & 63) == 0) {
            int r0 = (k << 3) + ((tid >> 6) << 1);   // rows r0, r0+1 for this wave
            hi32[r0]     = (unsigned int)bh;
            hi32[r0 + 1] = (unsigned int)(bh >> 32);
            lo32[r0]     = (unsigned int)bl;
            lo32[r0 + 1] = (unsigned int)(bl >> 32);
        }
    }
    __syncthreads();

    // hysteresis: 8-connected flood of `low` seeded at `high`; wave 0, row-per-lane
    if (tid < 64) {
        unsigned int lw  = (tid < 32) ? lo32[tid] : 0u;
        unsigned int cur = (tid < 32) ? hi32[tid] : 0u;
        for (;;) {
            unsigned int sp  = cur | (cur << 1) | (cur >> 1);
            unsigned int upv = (unsigned int)__shfl((int)sp, (tid + 63) & 63, 64);
            if (tid == 0) upv = 0u;
            unsigned int dnv = (unsigned int)__shfl((int)sp, (tid + 1) & 63, 64);
            unsigned int nxt = (sp | upv | dnv) & lw;
            bool ch = (nxt != cur);
            cur = nxt;
            if (__ballot((int)ch) == 0ull) break;
        }
        if (tid < 32) fin32[tid] = cur;
    }
    __syncthreads();

    // write out: float4 per thread, p = 4*tid
    {
        int p = tid << 2, i = p >> 5, j = p & 31;
        unsigned int row = fin32[i];
        float4 o;
        o.x = ((row >> (j    )) & 1u) ? 1.0f : -1.0f;
        o.y = ((row >> (j + 1)) & 1u) ? 1.0f : -1.0f;
        o.z = ((row >> (j + 2)) & 1u) ? 1.0f : -1.0f;
        o.w = ((row >> (j + 3)) & 1u) ? 1.0f : -1.0f;
        ((float4*)(out + (size_t)b * NPIX))[tid] = o;
    }
}

extern "C" void kernel_launch(void* const* d_in, const int* in_sizes, int n_in,
                              void* d_out, int out_size, void* d_ws, size_t ws_size,
                              hipStream_t stream) {
    const float* x    = (const float*)d_in[0];
    const float* mask = (const float*)d_in[1];
    float* out        = (float*)d_out;
    float* ws_bleed   = (float*)d_ws;
    unsigned int* ws_er = (unsigned int*)(ws_bleed + NPIX);
    float* ws_gk      = (float*)(ws_er + 32);
    int Bn = in_sizes[0] / (3 * NPIX);

    hipLaunchKernelGGL(canny_pre, dim3(1), dim3(256), 0, stream, x, mask, ws_bleed, ws_er, ws_gk);
    hipLaunchKernelGGL(canny_main, dim3(Bn), dim3(256), 0, stream, x, ws_bleed, ws_er, ws_gk, out);
}

// Round 5
// 51.648 us; speedup vs baseline: 1.5755x; 1.2186x over previous
//
#include <hip/hip_runtime.h>
#include <math.h>

#pragma clang fp contract(off)

#define NPIX 1024

// ---------------------------------------------------------------------------
// 9-tap gaussian (sigma=1, lw=4): phi in f64, normalized with numpy's pairwise
// sum order, cast to f32 — matches jnp.asarray(GAUSS_K, float32).
// Only computed in canny_pre; main reads ws_gk.
// ---------------------------------------------------------------------------
__device__ __forceinline__ void compute_gk(float gk[9]) {
    double phi[9];
    #pragma unroll
    for (int t = 0; t < 9; ++t) {
        double d = (double)(t - 4);
        phi[t] = exp(-0.5 * d * d);
    }
    double s = (((phi[0] + phi[1]) + (phi[2] + phi[3])) +
                ((phi[4] + phi[5]) + (phi[6] + phi[7]))) + phi[8];
    #pragma unroll
    for (int t = 0; t < 9; ++t) gk[t] = (float)(phi[t] / s);
}

// zero-padded / edge-clamped reads of a 32x32 float tile (row stride 32)
__device__ __forceinline__ float ldz(const float* b, int i, int j) {
    return (i >= 0 && i < 32 && j >= 0 && j < 32) ? b[(i << 5) + j] : 0.0f;
}
__device__ __forceinline__ float ldc(const float* b, int i, int j) {
    i = i < 0 ? 0 : (i > 31 ? 31 : i);
    j = j < 0 ? 0 : (j > 31 ? 31 : j);
    return b[(i << 5) + j];
}

// NMS interpolation check on plain 32x32 mag tile (pre-kernel only)
__device__ __forceinline__ bool nms2(const float* mag, int i, int j, float m, float w,
                                     int p2i, int p2j, int p1i, int p1j,
                                     int m2i, int m2j, int m1i, int m1j) {
    float omw = 1.0f - w;
    float ip = ldz(mag, i + p2i, j + p2j) * w + ldz(mag, i + p1i, j + p1j) * omw;
    float im = ldz(mag, i + m2i, j + m2j) * w + ldz(mag, i + m1i, j + m1j) * omw;
    return (ip <= m) && (im <= m);
}

// ---------------------------------------------------------------------------
// Kernel A (1 block): gk -> ws_gk; bleed+1e-12 -> ws_bleed;
// er = erode3x3(mask!=0) & (mag2(batch0) > 0) -> ws_er.
// ---------------------------------------------------------------------------
__global__ __launch_bounds__(256) void canny_pre(const float* __restrict__ x,
                                                 const float* __restrict__ mask,
                                                 float* __restrict__ ws_bleed,
                                                 unsigned int* __restrict__ ws_er,
                                                 float* __restrict__ ws_gk) {
    __shared__ float A[NPIX], Bf[NPIX], C[NPIX], D[NPIX], BL[NPIX];
    __shared__ unsigned int er32[32];
    const int tid = threadIdx.x;
    float gk[9];
    compute_gk(gk);
    if (tid < 9) ws_gk[tid] = gk[tid];

    #pragma unroll
    for (int k = 0; k < 4; ++k) { int p = tid + (k << 8); A[p] = mask[p]; }
    if (tid < 32) er32[tid] = 0u;
    __syncthreads();

    #pragma unroll
    for (int k = 0; k < 4; ++k) {
        int p = tid + (k << 8), i = p >> 5, j = p & 31;
        float s = 0.0f;
        #pragma unroll
        for (int t = 0; t < 9; ++t) s = __fmaf_rn(gk[t], ldz(A, i + t - 4, j), s);
        Bf[p] = s;
    }
    __syncthreads();
    #pragma unroll
    for (int k = 0; k < 4; ++k) {
        int p = tid + (k << 8), i = p >> 5, j = p & 31;
        float s = 0.0f;
        #pragma unroll
        for (int t = 0; t < 9; ++t) s = __fmaf_rn(gk[t], ldz(Bf, i, j + t - 4), s);
        BL[p] = s;
        ws_bleed[p] = s + 1e-12f;   // main divides by exactly this value
    }

    bool er2d[4];
    #pragma unroll
    for (int k = 0; k < 4; ++k) {
        int p = tid + (k << 8), i = p >> 5, j = p & 31;
        bool e = true;
        for (int di = -1; di <= 1; ++di)
            for (int dj = -1; dj <= 1; ++dj) {
                int ii = i + di, jj = j + dj;
                e = e && (ii >= 0 && ii < 32 && jj >= 0 && jj < 32) && (A[(ii << 5) + jj] != 0.0f);
            }
        er2d[k] = e;
    }
    __syncthreads();

    #pragma unroll
    for (int k = 0; k < 4; ++k) {
        int p = tid + (k << 8);
        float r = x[p]            * 0.5f + 0.5f;
        float g = x[p + NPIX]     * 0.5f + 0.5f;
        float b = x[p + 2 * NPIX] * 0.5f + 0.5f;
        A[p] = r * 0.299f + g * 0.587f + b * 0.114f;
    }
    __syncthreads();
    #pragma unroll
    for (int k = 0; k < 4; ++k) {
        int p = tid + (k << 8), i = p >> 5, j = p & 31;
        float s = 0.0f;
        #pragma unroll
        for (int t = 0; t < 9; ++t) s = __fmaf_rn(gk[t], ldz(A, i + t - 4, j), s);
        Bf[p] = s;
    }
    __syncthreads();
    #pragma unroll
    for (int k = 0; k < 4; ++k) {
        int p = tid + (k << 8), i = p >> 5, j = p & 31;
        float s = 0.0f;
        #pragma unroll
        for (int t = 0; t < 9; ++t) s = __fmaf_rn(gk[t], ldz(Bf, i, j + t - 4), s);
        A[p] = s;
    }
    __syncthreads();
    #pragma unroll
    for (int k = 0; k < 4; ++k) { int p = tid + (k << 8); A[p] = A[p] / (BL[p] + 1e-12f); }
    __syncthreads();
    #pragma unroll
    for (int k = 0; k < 4; ++k) { int p = tid + (k << 8), i = p >> 5, j = p & 31;
        Bf[p] = ldc(A, i, j + 1) - ldc(A, i, j - 1); }
    __syncthreads();
    #pragma unroll
    for (int k = 0; k < 4; ++k) { int p = tid + (k << 8), i = p >> 5, j = p & 31;
        C[p] = (ldc(Bf, i - 1, j) + 2.0f * ldc(Bf, i, j)) + ldc(Bf, i + 1, j); }
    __syncthreads();
    #pragma unroll
    for (int k = 0; k < 4; ++k) { int p = tid + (k << 8), i = p >> 5, j = p & 31;
        Bf[p] = ldc(A, i + 1, j) - ldc(A, i - 1, j); }
    __syncthreads();
    #pragma unroll
    for (int k = 0; k < 4; ++k) { int p = tid + (k << 8), i = p >> 5, j = p & 31;
        D[p] = (ldc(Bf, i, j - 1) + 2.0f * ldc(Bf, i, j)) + ldc(Bf, i, j + 1); }
    __syncthreads();
    #pragma unroll
    for (int k = 0; k < 4; ++k) {
        int p = tid + (k << 8), i = p >> 5, j = p & 31;
        if (er2d[k]) {
            float m2 = D[p] * D[p] + C[p] * C[p];
            if (m2 > 0.0f) atomicOr(&er32[i], 1u << j);
        }
    }
    __syncthreads();
    if (tid < 32) ws_er[tid] = er32[tid];
}

// ---------------------------------------------------------------------------
// Kernel B: one block per image.
// LDS: APAD 40x32 (4 zero-guard rows), BPAD 32x40 (4 zero-guard cols),
// MPAD 34x34 (1 zero-guard ring, stride 34). Branchless single-octant NMS.
// ---------------------------------------------------------------------------
__global__ __launch_bounds__(256) void canny_main(const float* __restrict__ x,
                                                  const float* __restrict__ ws_bleed,
                                                  const unsigned int* __restrict__ ws_er,
                                                  const float* __restrict__ ws_gk,
                                                  float* __restrict__ out) {
    __shared__ float APAD[40 * 32];    // (i+4)*32 + j
    __shared__ float BPAD[32 * 40];    // i*40 + (j+4)
    __shared__ float MPAD[34 * 34];    // (i+1)*34 + (j+1)
    __shared__ unsigned int er[32], hi32[32], lo32[32], fin32[32];
    const int tid = threadIdx.x;
    const int b = blockIdx.x;

    float gk[9];
    #pragma unroll
    for (int t = 0; t < 9; ++t) gk[t] = ws_gk[t];

    // zero guards
    APAD[tid < 128 ? tid : 1024 + tid] = 0.0f;
    { int r = tid >> 3, c8 = tid & 7; BPAD[r * 40 + c8 + (c8 < 4 ? 0 : 32)] = 0.0f; }
    #pragma unroll
    for (int t = 0; t < 5; ++t) { int idx = tid + (t << 8); if (idx < 34 * 34) MPAD[idx] = 0.0f; }
    if (tid < 32) er[tid] = ws_er[tid];

    // gray via float4 channel loads: p = 4*tid .. 4*tid+3
    {
        const float4* xr = (const float4*)(x + (size_t)b * 3 * NPIX);
        float4 r4 = xr[tid];
        float4 g4 = xr[tid + 256];
        float4 b4 = xr[tid + 512];
        int p = tid << 2, i = p >> 5, j = p & 31;
        float4 gy;
        gy.x = (r4.x * 0.5f + 0.5f) * 0.299f + (g4.x * 0.5f + 0.5f) * 0.587f + (b4.x * 0.5f + 0.5f) * 0.114f;
        gy.y = (r4.y * 0.5f + 0.5f) * 0.299f + (g4.y * 0.5f + 0.5f) * 0.587f + (b4.y * 0.5f + 0.5f) * 0.114f;
        gy.z = (r4.z * 0.5f + 0.5f) * 0.299f + (g4.z * 0.5f + 0.5f) * 0.587f + (b4.z * 0.5f + 0.5f) * 0.114f;
        gy.w = (r4.w * 0.5f + 0.5f) * 0.299f + (g4.w * 0.5f + 0.5f) * 0.587f + (b4.w * 0.5f + 0.5f) * 0.114f;
        *(float4*)&APAD[((i + 4) << 5) + j] = gy;
    }
    __syncthreads();

    // gaussian blur along H: APAD (guarded) -> BPAD interior
    #pragma unroll
    for (int k = 0; k < 4; ++k) {
        int p = tid + (k << 8), i = p >> 5, j = p & 31;
        float s = 0.0f;
        #pragma unroll
        for (int t = 0; t < 9; ++t) s = __fmaf_rn(gk[t], APAD[((i + t) << 5) + j], s);
        BPAD[i * 40 + j + 4] = s;
    }
    __syncthreads();

    // gaussian blur along W + divide by (bleed+1e-12): BPAD -> APAD interior
    #pragma unroll
    for (int k = 0; k < 4; ++k) {
        int p = tid + (k << 8), i = p >> 5, j = p & 31;
        float s = 0.0f;
        #pragma unroll
        for (int t = 0; t < 9; ++t) s = __fmaf_rn(gk[t], BPAD[i * 40 + j + t], s);
        APAD[((i + 4) << 5) + j] = s / ws_bleed[p];
    }
    __syncthreads();

    // fused sobel + mag: sm in APAD interior (clamped idx), mag -> MPAD interior
    float jsr[4], isr[4], mr[4];
    const float* S = &APAD[4 << 5];
    #pragma unroll
    for (int k = 0; k < 4; ++k) {
        int p = tid + (k << 8), i = p >> 5, j = p & 31;
        int im1 = i > 0 ? i - 1 : 0, ip1 = i < 31 ? i + 1 : 31;
        int jm1 = j > 0 ? j - 1 : 0, jp1 = j < 31 ? j + 1 : 31;
        float tm = S[(im1 << 5) + jp1] - S[(im1 << 5) + jm1];
        float t0 = S[(i   << 5) + jp1] - S[(i   << 5) + jm1];
        float tp = S[(ip1 << 5) + jp1] - S[(ip1 << 5) + jm1];
        float jsob = (tm + 2.0f * t0) + tp;
        float um = S[(ip1 << 5) + jm1] - S[(im1 << 5) + jm1];
        float u0 = S[(ip1 << 5) + j  ] - S[(im1 << 5) + j  ];
        float up = S[(ip1 << 5) + jp1] - S[(im1 << 5) + jp1];
        float isob = (um + 2.0f * u0) + up;
        jsr[k] = jsob; isr[k] = isob;
        float m = sqrtf((isob * isob + jsob * jsob) + 1e-9f);
        mr[k] = m;
        MPAD[(i + 1) * 34 + (j + 1)] = m;
    }
    __syncthreads();

    // Branchless NMS: octant = LAST true selector (later overwrites in ref).
    // o0=same&ai>=aj, o1=same&ai<=aj, o2=opp&ai<=aj, o3=opp&ai>=aj.
    // m-offsets are negatives of p-offsets; p2j == 1 for all octants.
    #pragma unroll
    for (int k = 0; k < 4; ++k) {
        int p = tid + (k << 8), i = p >> 5, j = p & 31;
        float iv = isr[k], jv = jsr[k], m = mr[k];
        float ai = fabsf(iv), aj = fabsf(jv);
        bool same = (iv >= 0.0f && jv >= 0.0f) || (iv <= 0.0f && jv <= 0.0f);
        bool opp  = (iv <= 0.0f && jv >= 0.0f) || (iv >= 0.0f && jv <= 0.0f);
        bool age  = (ai >= aj), ale = (ai <= aj);
        int oct = (opp && age) ? 3 : (opp && ale) ? 2 : (same && ale) ? 1 : 0;
        float ais = ai > 0.0f ? ai : 1.0f;
        float ajs = aj > 0.0f ? aj : 1.0f;
        float num = (oct == 3 || oct == 0) ? aj : ai;
        float den = (oct == 3) ? ais : (oct == 0) ? (ai + 1e-9f) : ajs;
        float w = num / den;
        float omw = 1.0f - w;
        int p2i = (oct >= 2) ? -1 : 1;                      // p2 = (p2i, 1)
        int p1i = (oct == 0) ? 1 : (oct == 3) ? -1 : 0;     // p1 = (p1i, p1j)
        int p1j = (oct == 1 || oct == 2) ? 1 : 0;
        int base = (i + 1) * 34 + (j + 1);
        float ip = MPAD[base + p2i * 34 + 1] * w + MPAD[base + p1i * 34 + p1j] * omw;
        float im = MPAD[base - p2i * 34 - 1] * w + MPAD[base - p1i * 34 - p1j] * omw;
        bool lm = (ip <= m) && (im <= m);
        bool eb = (er[i] >> j) & 1u;
        unsigned long long bh = __ballot(lm && eb && (m >= 0.2f));
        unsigned long long bl = __ballot(lm && eb && (m >= 0.1f));
        if ((tid & 63) == 0) {
            int r0 = (k << 3) + ((tid >> 6) << 1);
            hi32[r0]     = (unsigned int)bh;
            hi32[r0 + 1] = (unsigned int)(bh >> 32);
            lo32[r0]     = (unsigned int)bl;
            lo32[r0 + 1] = (unsigned int)(bl >> 32);
        }
    }
    __syncthreads();

    // hysteresis: 8-connected flood of `low` seeded at `high`; wave 0, row-per-lane
    if (tid < 64) {
        unsigned int lw  = (tid < 32) ? lo32[tid] : 0u;
        unsigned int cur = (tid < 32) ? hi32[tid] : 0u;
        for (;;) {
            unsigned int sp  = cur | (cur << 1) | (cur >> 1);
            unsigned int upv = (unsigned int)__shfl((int)sp, (tid + 63) & 63, 64);
            if (tid == 0) upv = 0u;
            unsigned int dnv = (unsigned int)__shfl((int)sp, (tid + 1) & 63, 64);
            unsigned int nxt = (sp | upv | dnv) & lw;
            bool ch = (nxt != cur);
            cur = nxt;
            if (__ballot((int)ch) == 0ull) break;
        }
        if (tid < 32) fin32[tid] = cur;
    }
    __syncthreads();

    // write out: float4 per thread
    {
        int p = tid << 2, i = p >> 5, j = p & 31;
        unsigned int row = fin32[i];
        float4 o;
        o.x = ((row >> (j    )) & 1u) ? 1.0f : -1.0f;
        o.y = ((row >> (j + 1)) & 1u) ? 1.0f : -1.0f;
        o.z = ((row >> (j + 2)) & 1u) ? 1.0f : -1.0f;
        o.w = ((row >> (j + 3)) & 1u) ? 1.0f : -1.0f;
        ((float4*)(out + (size_t)b * NPIX))[tid] = o;
    }
}

extern "C" void kernel_launch(void* const* d_in, const int* in_sizes, int n_in,
                              void* d_out, int out_size, void* d_ws, size_t ws_size,
                              hipStream_t stream) {
    const float* x    = (const float*)d_in[0];
    const float* mask = (const float*)d_in[1];
    float* out        = (float*)d_out;
    float* ws_bleed   = (float*)d_ws;
    unsigned int* ws_er = (unsigned int*)(ws_bleed + NPIX);
    float* ws_gk      = (float*)(ws_er + 32);
    int Bn = in_sizes[0] / (3 * NPIX);

    hipLaunchKernelGGL(canny_pre, dim3(1), dim3(256), 0, stream, x, mask, ws_bleed, ws_er, ws_gk);
    hipLaunchKernelGGL(canny_main, dim3(Bn), dim3(256), 0, stream, x, ws_bleed, ws_er, ws_gk, out);
}